// Round 7
// baseline (235.465 us; speedup 1.0000x reference)
//
#include <hip/hip_runtime.h>
#include <hip/hip_fp16.h>

#define N_NODES 50000
#define N_EDGES 800000
#define NREL 32
#define NEG_SLOPE 0.2f
#define SCAN_NB ((N_NODES + 255) / 256)   // 196

// ---------------- CSR build ----------------
__global__ __launch_bounds__(256) void hist_kernel(const int* __restrict__ ei,
                                                   int* __restrict__ counts) {
    int e = blockIdx.x * 256 + threadIdx.x;
    if (e < N_EDGES) atomicAdd(&counts[ei[N_EDGES + e]], 1);
}

// block-level exclusive scan
__global__ __launch_bounds__(256) void scan1_kernel(const int* __restrict__ counts,
                                                    int* __restrict__ offsets,
                                                    int* __restrict__ blocksums) {
    __shared__ int sh[256];
    int tid = threadIdx.x;
    int i = blockIdx.x * 256 + tid;
    int v = (i < N_NODES) ? counts[i] : 0;
    sh[tid] = v;
    __syncthreads();
    #pragma unroll
    for (int off = 1; off < 256; off <<= 1) {
        int t = (tid >= off) ? sh[tid - off] : 0;
        __syncthreads();
        sh[tid] += t;
        __syncthreads();
    }
    if (i < N_NODES) offsets[i] = sh[tid] - v;
    if (tid == 255) blocksums[blockIdx.x] = sh[255];
}

__global__ __launch_bounds__(256) void scan2_kernel(int* __restrict__ blocksums,
                                                    int* __restrict__ blockoff) {
    __shared__ int sh[256];
    int tid = threadIdx.x;
    int v = (tid < SCAN_NB) ? blocksums[tid] : 0;
    sh[tid] = v;
    __syncthreads();
    #pragma unroll
    for (int off = 1; off < 256; off <<= 1) {
        int t = (tid >= off) ? sh[tid - off] : 0;
        __syncthreads();
        sh[tid] += t;
        __syncthreads();
    }
    if (tid < SCAN_NB) blockoff[tid] = sh[tid] - v;
}

__global__ __launch_bounds__(256) void scan3_kernel(int* __restrict__ offsets,
                                                    const int* __restrict__ blockoff,
                                                    int* __restrict__ cursor) {
    int i = blockIdx.x * 256 + threadIdx.x;
    if (i < N_NODES) {
        int o = offsets[i] + blockoff[blockIdx.x];
        offsets[i] = o;
        cursor[i] = o;
    }
}

// pack (src, type): src < 2^16, type < 2^5
__global__ __launch_bounds__(256) void scatter_kernel(const int* __restrict__ ei,
                                                      const int* __restrict__ etype,
                                                      int* __restrict__ cursor,
                                                      int* __restrict__ elist) {
    int e = blockIdx.x * 256 + threadIdx.x;
    if (e >= N_EDGES) return;
    int s = ei[e];
    int d = ei[N_EDGES + e];
    int t = etype[e];
    int pos = atomicAdd(&cursor[d], 1);
    elist[pos] = (s << 5) | t;
}

// ---------------- node transform: xh = x@W (fp16, [N][C][H] layout), a_src, a_dst ----------------
// Wave = head h (col = h*64+lane). __launch_bounds__(256,2) raises the VGPR
// budget so Wreg[64] is truly register-resident (round-6 profile showed
// VGPR_Count=44 -> W was being re-loaded from L2 every iteration).
__global__ __launch_bounds__(256, 2) void node_xform(
    const float* __restrict__ x, const float* __restrict__ W,
    const float* __restrict__ att_src, const float* __restrict__ att_dst,
    __half* __restrict__ xh, float* __restrict__ a_src, float* __restrict__ a_dst)
{
    int tid = threadIdx.x;
    int lane = tid & 63;
    int h = tid >> 6;          // wave == head
    int col = h * 64 + lane;

    float Wreg[64];
    #pragma unroll
    for (int k = 0; k < 64; ++k) Wreg[k] = W[k * 256 + col];
    float asv = att_src[col];
    float adv = att_dst[col];

    for (int n = blockIdx.x * 2; n < N_NODES; n += gridDim.x * 2) {
        const float* __restrict__ xa = x + (size_t)n * 64;
        const float* __restrict__ xb = xa + 64;
        float accA = 0.f, accB = 0.f;
        #pragma unroll
        for (int k = 0; k < 64; ++k) {
            float wk = Wreg[k];
            accA = fmaf(xa[k], wk, accA);
            accB = fmaf(xb[k], wk, accB);
        }
        xh[(size_t)n * 256 + lane * 4 + h]       = __float2half(accA);
        xh[(size_t)(n + 1) * 256 + lane * 4 + h] = __float2half(accB);

        float asA = accA * asv, adA = accA * adv;
        float asB = accB * asv, adB = accB * adv;
        #pragma unroll
        for (int m = 32; m >= 1; m >>= 1) {
            asA += __shfl_xor(asA, m);
            adA += __shfl_xor(adA, m);
            asB += __shfl_xor(asB, m);
            adB += __shfl_xor(adB, m);
        }
        if (lane == 0) {
            a_src[n * 4 + h] = asA;
            a_dst[n * 4 + h] = adA;
            a_src[(n + 1) * 4 + h] = asB;
            a_dst[(n + 1) * 4 + h] = adB;
        }
    }
}

// ---------------- relation table: a_edge_r[r][h] ----------------
__global__ __launch_bounds__(64) void rel_kernel(
    const float* __restrict__ rel_emb, const float* __restrict__ W_e,
    const float* __restrict__ att_edge, float* __restrict__ a_edge_r)
{
    int r = blockIdx.x;
    int lane = threadIdx.x;
    int h = lane >> 4;
    int i16 = lane & 15;

    float rr = rel_emb[r * 64 + lane];
    float4 acc = {0.f, 0.f, 0.f, 0.f};
    #pragma unroll
    for (int k = 0; k < 64; ++k) {
        float rv = __shfl(rr, k);
        float4 wv = *(const float4*)(W_e + k * 256 + h * 64 + i16 * 4);
        acc.x += rv * wv.x; acc.y += rv * wv.y;
        acc.z += rv * wv.z; acc.w += rv * wv.w;
    }
    float4 aev = *(const float4*)(att_edge + h * 64 + i16 * 4);
    float ae = acc.x * aev.x + acc.y * aev.y + acc.z * aev.z + acc.w * aev.w;
    #pragma unroll
    for (int m = 8; m >= 1; m >>= 1) ae += __shfl_xor(ae, m);
    if (i16 == 0) a_edge_r[r * 4 + h] = ae;
}

// ---------------- fused aggregate ----------------
// Phase A: lane computes exp for ITS edge of a 64-edge chunk -> LDS (wave-synchronous).
// Phase B: per-edge broadcast from LDS + 8B gather + 4 FMA (unroll 8 for MLP depth).
__global__ __launch_bounds__(256) void aggregate(
    const int* __restrict__ offsets, const int* __restrict__ counts,
    const int* __restrict__ elist, const float* __restrict__ a_src,
    const float* __restrict__ a_dst, const float* __restrict__ a_edge_r,
    const __half* __restrict__ xh, const float* __restrict__ bias,
    float* __restrict__ out)
{
    __shared__ float4 exsh[4][64];
    __shared__ int    ssh[4][64];
    int lane = threadIdx.x & 63;
    int warp = threadIdx.x >> 6;
    float bv = bias[lane];

    for (int d = blockIdx.x * 4 + warp; d < N_NODES; d += gridDim.x * 4) {
        int beg = offsets[d];
        int deg = counts[d];
        float4 advec = ((const float4*)a_dst)[d];

        float n0 = 0.f, n1 = 0.f, n2 = 0.f, n3 = 0.f;
        float d0 = 0.f, d1 = 0.f, d2 = 0.f, d3 = 0.f;

        for (int base = 0; base < deg; base += 64) {
            int m = deg - base; if (m > 64) m = 64;

            float4 ev = make_float4(0.f, 0.f, 0.f, 0.f);
            int s = 0;
            if (lane < m) {
                int pk = elist[beg + base + lane];
                s = pk >> 5;
                int t = pk & 31;
                float4 as = ((const float4*)a_src)[s];
                float4 ae = ((const float4*)a_edge_r)[t];
                float a0 = as.x + advec.x + ae.x; a0 = a0 > 0.f ? a0 : NEG_SLOPE * a0;
                float a1 = as.y + advec.y + ae.y; a1 = a1 > 0.f ? a1 : NEG_SLOPE * a1;
                float a2 = as.z + advec.z + ae.z; a2 = a2 > 0.f ? a2 : NEG_SLOPE * a2;
                float a3 = as.w + advec.w + ae.w; a3 = a3 > 0.f ? a3 : NEG_SLOPE * a3;
                ev.x = __expf(a0); ev.y = __expf(a1);
                ev.z = __expf(a2); ev.w = __expf(a3);
            }
            d0 += ev.x; d1 += ev.y; d2 += ev.z; d3 += ev.w;
            exsh[warp][lane] = ev;   // wave-private rows; wave-synchronous RAW
            ssh[warp][lane]  = s;

            #pragma unroll 8
            for (int j = 0; j < m; ++j) {
                float4 e = exsh[warp][j];   // broadcast read (no conflict)
                int sj = ssh[warp][j];
                const __half2* __restrict__ xr =
                    (const __half2*)(xh + (size_t)sj * 256 + lane * 4);
                __half2 p0 = xr[0], p1 = xr[1];
                float2 f0 = __half22float2(p0), f1 = __half22float2(p1);
                n0 = fmaf(e.x, f0.x, n0);
                n1 = fmaf(e.y, f0.y, n1);
                n2 = fmaf(e.z, f1.x, n2);
                n3 = fmaf(e.w, f1.y, n3);
            }
        }

        // butterfly-reduce denominators across the wave (once per node)
        #pragma unroll
        for (int msk = 32; msk >= 1; msk >>= 1) {
            d0 += __shfl_xor(d0, msk);
            d1 += __shfl_xor(d1, msk);
            d2 += __shfl_xor(d2, msk);
            d3 += __shfl_xor(d3, msk);
        }

        float r = 0.f;
        if (deg > 0)
            r = 0.25f * (n0 / d0 + n1 / d1 + n2 / d2 + n3 / d3);
        out[(size_t)d * 64 + lane] = r + bv;
    }
}

extern "C" void kernel_launch(void* const* d_in, const int* in_sizes, int n_in,
                              void* d_out, int out_size, void* d_ws, size_t ws_size,
                              hipStream_t stream) {
    const float* x        = (const float*)d_in[0];
    const int*   ei       = (const int*)  d_in[1];
    const int*   etype    = (const int*)  d_in[2];
    const float* rel_emb  = (const float*)d_in[3];
    const float* W        = (const float*)d_in[4];
    const float* W_e      = (const float*)d_in[5];
    const float* att_src  = (const float*)d_in[6];
    const float* att_dst  = (const float*)d_in[7];
    const float* att_edge = (const float*)d_in[8];
    const float* bias     = (const float*)d_in[9];
    float* out = (float*)d_out;

    // workspace layout
    char* ws = (char*)d_ws;
    __half* xh      = (__half*)ws;                              // N*256 halfs = 25.6 MB
    char* p = ws + (size_t)N_NODES * 256 * 2;
    float* a_src    = (float*)p;              p += N_NODES * 4 * 4;
    float* a_dst    = (float*)p;              p += N_NODES * 4 * 4;
    float* a_edge_r = (float*)p;              p += NREL * 4 * 4;
    int*   counts   = (int*)p;                p += N_NODES * 4;
    int*   offsets  = (int*)p;                p += N_NODES * 4;
    int*   cursor   = (int*)p;                p += N_NODES * 4;
    int*   blocksums= (int*)p;                p += 256 * 4;
    int*   blockoff = (int*)p;                p += 256 * 4;
    int*   elist    = (int*)p;                p += (size_t)N_EDGES * 4;

    hipMemsetAsync(counts, 0, N_NODES * sizeof(int), stream);
    hist_kernel<<<(N_EDGES + 255) / 256, 256, 0, stream>>>(ei, counts);
    scan1_kernel<<<SCAN_NB, 256, 0, stream>>>(counts, offsets, blocksums);
    scan2_kernel<<<1, 256, 0, stream>>>(blocksums, blockoff);
    scan3_kernel<<<SCAN_NB, 256, 0, stream>>>(offsets, blockoff, cursor);
    scatter_kernel<<<(N_EDGES + 255) / 256, 256, 0, stream>>>(ei, etype, cursor, elist);
    node_xform<<<1024, 256, 0, stream>>>(x, W, att_src, att_dst, xh, a_src, a_dst);
    rel_kernel<<<NREL, 64, 0, stream>>>(rel_emb, W_e, att_edge, a_edge_r);
    aggregate<<<(N_NODES + 3) / 4, 256, 0, stream>>>(offsets, counts, elist, a_src,
                                                     a_dst, a_edge_r, xh, bias, out);
}